// Round 1
// 436.131 us; speedup vs baseline: 1.1152x; 1.1152x over previous
//
#include <hip/hip_runtime.h>

#define NN 100000
#define NE 1600000
#define DIM0 11
#define H 128
#define NL 4
#define NG 4096
#define EPS 1e-5f

#define NBKT 391       // buckets of 256 nodes: bucket = dst >> 8
#define CAP 5120       // fixed bucket capacity (mean 4096, sigma 64 -> 16 sigma)
#define EPB 4096       // edges per block in scatter phase
static constexpr int NBB = (NE + EPB - 1) / EPB;  // 391

typedef _Float16 f16x8 __attribute__((ext_vector_type(8)));
typedef _Float16 f16x2 __attribute__((ext_vector_type(2)));
typedef float f32x4 __attribute__((ext_vector_type(4)));
typedef float f32x2 __attribute__((ext_vector_type(2)));

// r14 lesson: 2-node interleave in phase 1 doubled register demand -> scratch
// spill -> 154us. Single-node engine (VGPR 32, no spill) kept.
// This round: gather operand moved to fp8-e4m3 rows pre-scaled by dis[node]
// (h_pre = h * dis). Row = 128B instead of 256B -> per-XCD L2-miss working
// set 25.6MB -> 12.8MB, structural fetch floor 205MB -> 102MB. Residual /
// GEMM / LN path stays fp16. Per-edge dis[src] load + weight multiply chain
// eliminated (one dis[dst] scale after the quarter-combine).

// ---- fp8 helpers (OCP e4m3 on gfx950) ----

__device__ __forceinline__ uint2 pack_fp8x8(const float* v) {
    int lo = 0, hi = 0;
    lo = __builtin_amdgcn_cvt_pk_fp8_f32(v[0], v[1], lo, false);
    lo = __builtin_amdgcn_cvt_pk_fp8_f32(v[2], v[3], lo, true);
    hi = __builtin_amdgcn_cvt_pk_fp8_f32(v[4], v[5], hi, false);
    hi = __builtin_amdgcn_cvt_pk_fp8_f32(v[6], v[7], hi, true);
    return (uint2){(unsigned)lo, (unsigned)hi};
}

__device__ __forceinline__ void acc_fp8x8(uint2 u, float* a) {
    f32x2 p0 = __builtin_amdgcn_cvt_pk_f32_fp8((int)u.x, false);
    f32x2 p1 = __builtin_amdgcn_cvt_pk_f32_fp8((int)u.x, true);
    f32x2 p2 = __builtin_amdgcn_cvt_pk_f32_fp8((int)u.y, false);
    f32x2 p3 = __builtin_amdgcn_cvt_pk_f32_fp8((int)u.y, true);
    a[0] += p0[0]; a[1] += p0[1]; a[2] += p1[0]; a[3] += p1[1];
    a[4] += p2[0]; a[5] += p2[1]; a[6] += p3[0]; a[7] += p3[1];
}

// ---------------- init ----------------

__global__ void k_init(int* __restrict__ bfill, int* __restrict__ gstart, int* __restrict__ gend) {
    int i = blockIdx.x * 256 + threadIdx.x;
    if (i <= NBKT) bfill[i] = 0;
    if (i < NG) { gstart[i] = 0x7fffffff; gend[i] = 0; }
}

// ---------------- bucketed CSR build ----------------

__global__ __launch_bounds__(256) void k_bscatter(const int* __restrict__ src, const int* __restrict__ dst,
                                                  int* __restrict__ bfill, unsigned int* __restrict__ ebuf) {
    __shared__ int lc[NBKT];
    __shared__ int lbase[NBKT];
    int t = threadIdx.x;
    for (int i = t; i < NBKT; i += 256) lc[i] = 0;
    __syncthreads();
    int base = blockIdx.x * EPB;
    int rank[16];
    int bk[16];
    unsigned pk[16];
#pragma unroll
    for (int i = 0; i < 16; i++) {
        int e = base + i * 256 + t;
        if (e < NE) {
            int d = dst[e];
            int s = src[e];
            int b = d >> 8;
            bk[i] = b;
            pk[i] = (unsigned)s | ((unsigned)(d & 255) << 17);
            rank[i] = atomicAdd(&lc[b], 1);
        } else bk[i] = -1;
    }
    __syncthreads();
    for (int i = t; i < NBKT; i += 256)
        lbase[i] = i * CAP + (lc[i] ? atomicAdd(&bfill[i], lc[i]) : 0);
    __syncthreads();
#pragma unroll
    for (int i = 0; i < 16; i++) {
        if (bk[i] >= 0)
            ebuf[lbase[bk[i]] + rank[i]] = pk[i];
    }
}

// One block per bucket (391 blocks): count -> dis, scan -> rps/rpe, scatter -> col.
__global__ __launch_bounds__(256) void k_bcsr(const unsigned int* __restrict__ ebuf,
                                              const int* __restrict__ bfill,
                                              int* __restrict__ rps, int* __restrict__ rpe,
                                              int* __restrict__ col, float* __restrict__ dis) {
    __shared__ int lcnt[256];
    __shared__ int lfill[256];
    __shared__ int tmp[256];
    int t = threadIdx.x;
    int b = blockIdx.x;
    int cb = b * CAP;
    int ecnt = bfill[b];
    int n0 = b << 8;
    int nb = min(256, NN - n0);

    lcnt[t] = 0;
    lfill[t] = 0;
    __syncthreads();

    for (int i = t; i < ecnt; i += 256) {
        unsigned p = ebuf[cb + i];
        atomicAdd(&lcnt[p >> 17], 1);
    }
    __syncthreads();

    if (t < nb) dis[n0 + t] = rsqrtf((float)(lcnt[t] + 1));

    int v = lcnt[t];
    tmp[t] = v;
    __syncthreads();
    for (int off = 1; off < 256; off <<= 1) {
        int x = (t >= off) ? tmp[t - off] : 0;
        __syncthreads();
        tmp[t] += x;
        __syncthreads();
    }
    lcnt[t] = tmp[t] - v;   // exclusive scan
    __syncthreads();

    if (t < nb) {
        rps[n0 + t] = cb + lcnt[t];
        rpe[n0 + t] = cb + ((t < 255) ? lcnt[t + 1] : ecnt);
    }

    for (int i = t; i < ecnt; i += 256) {
        unsigned p = ebuf[cb + i];
        int dl = p >> 17;
        int s = (int)(p & 0x1FFFFu);
        col[cb + lcnt[dl] + atomicAdd(&lfill[dl], 1)] = s;
    }
}

// ---------------- embed: hh = fp16(relu(x @ W_embed + b)); hp = fp8(hh * dis) ----------------

__global__ __launch_bounds__(256) void k_embed(const float* __restrict__ x, const float* __restrict__ W,
                                               const float* __restrict__ b, _Float16* __restrict__ hh,
                                               const float* __restrict__ dis, uint2* __restrict__ hp) {
    __shared__ float Ws[DIM0 * H];
    __shared__ float bs[H];
    __shared__ float xs[16 * DIM0];
    int tid = threadIdx.x;
    for (int i = tid; i < DIM0 * H; i += 256) Ws[i] = W[i];
    if (tid < H) bs[tid] = b[tid];
    if (tid < 16 * DIM0) xs[tid] = x[(size_t)blockIdx.x * (16 * DIM0) + tid];
    __syncthreads();
    int nl = tid >> 4;
    int node = blockIdx.x * 16 + nl;
    int l4 = tid & 15;
    float dn = dis[node];
    f16x8 o;
    float hv[8];
#pragma unroll
    for (int j = 0; j < 8; j++) {
        int c = l4 * 8 + j;
        float acc = bs[c];
#pragma unroll
        for (int k = 0; k < DIM0; k++) acc += xs[nl * DIM0 + k] * Ws[k * H + c];
        float r = fmaxf(acc, 0.f);
        o[j] = (_Float16)r;
        hv[j] = r * dn;
    }
    *(f16x8*)&hh[(size_t)node * H + l4 * 8] = o;
    hp[(size_t)node * 16 + l4] = pack_fp8x8(hv);
}

// ---------------- W pack: W[l][k][n] fp32 -> B-fragment-layout fp16 ----------------

__global__ __launch_bounds__(256) void k_wpack(const float* __restrict__ W, _Float16* __restrict__ Wp) {
    int t = blockIdx.x * 256 + threadIdx.x;   // 8192 threads
    int lane = t & 63;
    int idx = t >> 6;          // 0..127
    int nt = idx & 7;
    int ks = (idx >> 3) & 3;
    int l = idx >> 5;
    int q = lane >> 4, l15 = lane & 15;
    const float* Wl = W + (size_t)l * H * H;
    _Float16* o = Wp + (size_t)idx * 512 + lane * 8;
#pragma unroll
    for (int j = 0; j < 8; j++)
        o[j] = (_Float16)(Wl[(ks * 32 + q * 8 + j) * H + nt * 16 + l15]);
}

// ---------------- fused layer: hout = relu(LN(agg(hin) @ W + b)) + hin ----------------
// Gather operand: hpin = fp8 rows of h*dis (128B/row). a = sum of h_pre over
// {self, neighbors}; agg = dn * a. Residual path reads fp16 hin. Epilogue
// writes both fp16 hout and fp8 hpout = (hout * dis).

__global__ __launch_bounds__(128, 8) void k_layer(const _Float16* __restrict__ hin,
                                                  _Float16* __restrict__ hout,
                                                  const uint2* __restrict__ hpin,
                                                  uint2* __restrict__ hpout,
                                                  const float* __restrict__ dis, const int* __restrict__ rps,
                                                  const int* __restrict__ rpe, const int* __restrict__ col,
                                                  const _Float16* __restrict__ Wp,
                                                  const float* __restrict__ bias,
                                                  const float* __restrict__ gamma,
                                                  const float* __restrict__ beta) {
    __shared__ _Float16 Ls[2][16][136];   // 8704 B
    int tid = threadIdx.x;
    int wave = tid >> 6;
    int lane = tid & 63;
    int q = lane >> 4, l4 = lane & 15;
    int nbase = blockIdx.x * 32 + wave * 16;

    // ---- phase 1: gather 16 nodes into Ls ----
#pragma unroll 1
    for (int i = 0; i < 16; i++) {
        int node = __builtin_amdgcn_readfirstlane(nbase + i);
        float a[8];
#pragma unroll
        for (int j = 0; j < 8; j++) a[j] = 0.f;
        float dn = 0.f;
        if (node < NN) {
            dn = dis[node];
            if (q == 0) {  // self-loop counted once
                uint2 sv = hpin[(size_t)node * 16 + l4];
                acc_fp8x8(sv, a);
            }
            int e0 = rps[node], e1 = rpe[node];
            int e = e0 + q;
            for (; e + 12 < e1; e += 16) {
                int s0 = col[e];
                int s1 = col[e + 4];
                int s2 = col[e + 8];
                int s3 = col[e + 12];
                uint2 v0 = hpin[(size_t)s0 * 16 + l4];
                uint2 v1 = hpin[(size_t)s1 * 16 + l4];
                uint2 v2 = hpin[(size_t)s2 * 16 + l4];
                uint2 v3 = hpin[(size_t)s3 * 16 + l4];
                acc_fp8x8(v0, a);
                acc_fp8x8(v1, a);
                acc_fp8x8(v2, a);
                acc_fp8x8(v3, a);
            }
            for (; e < e1; e += 4) {
                int s = col[e];
                uint2 v = hpin[(size_t)s * 16 + l4];
                acc_fp8x8(v, a);
            }
        }
        // combine the 4 edge-slot quarters
#pragma unroll
        for (int j = 0; j < 8; j++) {
            a[j] += __shfl_xor(a[j], 16, 64);
            a[j] += __shfl_xor(a[j], 32, 64);
        }
        if (q == 0) {
            f16x8 o;
#pragma unroll
            for (int j = 0; j < 8; j++) o[j] = (_Float16)(a[j] * dn);
            *(f16x8*)&Ls[wave][i][l4 * 8] = o;
        }
    }

    // ---- phase 2: read A-fragments into registers, then GEMM + LN (Ls reused) ----
    f16x8 af[4];
#pragma unroll
    for (int ks = 0; ks < 4; ks++)
        af[ks] = *(const f16x8*)&Ls[wave][l4][ks * 32 + q * 8];

    float bb[8], gm[8], bt[8];
#pragma unroll
    for (int nt = 0; nt < 8; nt++) {
        bb[nt] = bias[nt * 16 + l4];
        gm[nt] = gamma[nt * 16 + l4];
        bt[nt] = beta[nt * 16 + l4];
    }

    const f16x8* wp8 = (const f16x8*)Wp;
    f32x4 acc[8];
#pragma unroll
    for (int nt = 0; nt < 8; nt++) {
        acc[nt] = (f32x4){0.f, 0.f, 0.f, 0.f};
#pragma unroll
        for (int ks = 0; ks < 4; ks++) {
            f16x8 bf = wp8[(ks * 8 + nt) * 64 + lane];
            acc[nt] = __builtin_amdgcn_mfma_f32_16x16x32_f16(af[ks], bf, acc[nt], 0, 0, 0);
        }
#pragma unroll
        for (int r = 0; r < 4; r++) acc[nt][r] += bb[nt];
    }

    float mu[4], rs[4];
#pragma unroll
    for (int r = 0; r < 4; r++) {
        float s = 0.f;
#pragma unroll
        for (int nt = 0; nt < 8; nt++) s += acc[nt][r];
#pragma unroll
        for (int off = 8; off > 0; off >>= 1) s += __shfl_xor(s, off, 64);
        mu[r] = s * (1.f / 128.f);
    }
#pragma unroll
    for (int r = 0; r < 4; r++) {
        float v = 0.f;
#pragma unroll
        for (int nt = 0; nt < 8; nt++) {
            float d = acc[nt][r] - mu[r];
            v += d * d;
        }
#pragma unroll
        for (int off = 8; off > 0; off >>= 1) v += __shfl_xor(v, off, 64);
        rs[r] = rsqrtf(v * (1.f / 128.f) + EPS);
    }

    // overwrite Ls with LN output (af already in registers)
#pragma unroll
    for (int nt = 0; nt < 8; nt++)
#pragma unroll
        for (int r = 0; r < 4; r++) {
            float o = fmaxf((acc[nt][r] - mu[r]) * rs[r] * gm[nt] + bt[nt], 0.f);
            Ls[wave][q * 4 + r][nt * 16 + l4] = (_Float16)o;
        }

    // epilogue: residual add (hin) + coalesced store to hout + fp8 gather copy
    const f16x8* hi8 = (const f16x8*)hin;
    f16x8* ho8 = (f16x8*)hout;
#pragma unroll
    for (int it = 0; it < 4; it++) {
        int c = it * 64 + lane;
        int rr = c >> 4, ck = c & 15;
        int row = nbase + rr;
        if (row < NN) {
            f16x8 ln = *(const f16x8*)&Ls[wave][rr][ck * 8];
            f16x8 res = hi8[(size_t)row * 16 + ck];
            float dn2 = dis[row];
            f16x8 o;
            float hv[8];
#pragma unroll
            for (int j = 0; j < 8; j++) {
                float s = (float)ln[j] + (float)res[j];
                o[j] = (_Float16)s;
                hv[j] = s * dn2;
            }
            ho8[(size_t)row * 16 + ck] = o;
            hpout[(size_t)row * 16 + ck] = pack_fp8x8(hv);
        }
    }
}

// ---------------- pooling ----------------

__global__ void k_range(const int* __restrict__ batch, int* __restrict__ gstart, int* __restrict__ gend) {
    int n = blockIdx.x * 256 + threadIdx.x;
    if (n < NN) {
        int g = batch[n];
        atomicMin(&gstart[g], n);
        atomicMax(&gend[g], n + 1);
    }
}

// One wave per graph; lane = (node slot p4, col group l4); f16x8 loads, 4 nodes/iter.
__global__ __launch_bounds__(256) void k_pool(const _Float16* __restrict__ hh, const int* __restrict__ gstart,
                                              const int* __restrict__ gend, const float* __restrict__ Wout,
                                              const float* __restrict__ bout, float* __restrict__ out) {
    int tid = threadIdx.x;
    int lane = tid & 63;
    int p4 = lane >> 4;     // node slot 0..3
    int l4 = lane & 15;     // cols l4*8 .. +7
    int g = blockIdx.x * 4 + (tid >> 6);
    if (g >= NG) return;

    int s = gstart[g], e = gend[g];
    const f16x8* h8 = (const f16x8*)hh;
    float acc[8];
#pragma unroll
    for (int j = 0; j < 8; j++) acc[j] = 0.f;
    for (int n = s + p4; n < e; n += 4) {
        f16x8 v = h8[(size_t)n * 16 + l4];
#pragma unroll
        for (int j = 0; j < 8; j++) acc[j] += (float)v[j];
    }
    // combine node slots
#pragma unroll
    for (int j = 0; j < 8; j++) {
        acc[j] += __shfl_xor(acc[j], 16, 64);
        acc[j] += __shfl_xor(acc[j], 32, 64);
    }
    float p = 0.f;
#pragma unroll
    for (int j = 0; j < 8; j++) p += acc[j] * Wout[l4 * 8 + j];
    // reduce across the 16 col groups
#pragma unroll
    for (int off = 8; off > 0; off >>= 1) p += __shfl_xor(p, off, 64);
    if (lane == 0) {
        float inv = 1.f / (float)max(e - s, 1);
        out[g] = p * inv + bout[0];
    }
}

// ---------------- launcher ----------------

extern "C" void kernel_launch(void* const* d_in, const int* in_sizes, int n_in,
                              void* d_out, int out_size, void* d_ws, size_t ws_size,
                              hipStream_t stream) {
    const float* x       = (const float*)d_in[0];
    const int*   edge    = (const int*)d_in[1];
    const int*   batch   = (const int*)d_in[2];
    const float* W_embed = (const float*)d_in[3];
    const float* b_embed = (const float*)d_in[4];
    const float* W_gnn   = (const float*)d_in[5];
    const float* b_gnn   = (const float*)d_in[6];
    const float* gamma   = (const float*)d_in[7];
    const float* beta    = (const float*)d_in[8];
    const float* W_out   = (const float*)d_in[9];
    const float* b_out   = (const float*)d_in[10];
    float* out = (float*)d_out;

    char* ws = (char*)d_ws;
    size_t off = 0;
    auto alloc = [&](size_t bytes) -> char* {
        char* p = ws + off;
        off += (bytes + 255) & ~(size_t)255;
        return p;
    };
    _Float16*     hh0  = (_Float16*)alloc((size_t)NN * H * 2);
    _Float16*     hh1  = (_Float16*)alloc((size_t)NN * H * 2);
    uint2*        hp0  = (uint2*)alloc((size_t)NN * H);       // fp8 gather copies
    uint2*        hp1  = (uint2*)alloc((size_t)NN * H);
    _Float16*     Wp   = (_Float16*)alloc((size_t)NL * 4 * 8 * 512 * 2);
    float*        dis  = (float*)alloc((size_t)NN * 4);
    int*          rps  = (int*)alloc((size_t)NN * 4);
    int*          rpe  = (int*)alloc((size_t)NN * 4);
    int*          col  = (int*)alloc((size_t)NBKT * CAP * 4);
    unsigned int* ebuf = (unsigned int*)alloc((size_t)NBKT * CAP * 4);
    int*          bfill = (int*)alloc((NBKT + 1) * 4);
    int*   gstart = (int*)alloc((size_t)NG * 4);
    int*   gend   = (int*)alloc((size_t)NG * 4);

    const int* srcp = edge;
    const int* dstp = edge + NE;

    k_init<<<(NG + 255) / 256, 256, 0, stream>>>(bfill, gstart, gend);
    k_bscatter<<<NBB, 256, 0, stream>>>(srcp, dstp, bfill, ebuf);
    k_bcsr<<<NBKT, 256, 0, stream>>>(ebuf, bfill, rps, rpe, col, dis);

    k_wpack<<<32, 256, 0, stream>>>(W_gnn, Wp);
    k_embed<<<NN / 16, 256, 0, stream>>>(x, W_embed, b_embed, hh0, dis, hp0);

    // ping-pong: L0 hh0->hh1, L1 hh1->hh0, L2 hh0->hh1, L3 hh1->hh0
    _Float16* hb[2] = {hh0, hh1};
    uint2*    hp[2] = {hp0, hp1};
    for (int l = 0; l < NL; l++) {
        k_layer<<<(NN + 31) / 32, 128, 0, stream>>>(hb[l & 1], hb[(l & 1) ^ 1],
                                                    hp[l & 1], hp[(l & 1) ^ 1],
                                                    dis, rps, rpe, col,
                                                    Wp + (size_t)l * 4 * 8 * 512,
                                                    b_gnn + l * H, gamma + l * H, beta + l * H);
    }

    k_range<<<(NN + 255) / 256, 256, 0, stream>>>(batch, gstart, gend);
    k_pool<<<NG / 4, 256, 0, stream>>>(hh0, gstart, gend, W_out, b_out, out);
}

// Round 3
// 371.254 us; speedup vs baseline: 1.3101x; 1.1748x over previous
//
#include <hip/hip_runtime.h>

#define NN 100000
#define NE 1600000
#define DIM0 11
#define H 128
#define NL 4
#define NG 4096
#define EPS 1e-5f

#define NBKT 391       // buckets of 256 nodes: bucket = dst >> 8
#define CAP 5120       // fixed bucket capacity (mean 4096, sigma 64 -> 16 sigma)
#define EPB 4096       // edges per block in scatter phase
static constexpr int NBB = (NE + EPB - 1) / EPB;  // 391

typedef _Float16 f16x8 __attribute__((ext_vector_type(8)));
typedef _Float16 f16x2 __attribute__((ext_vector_type(2)));
typedef float f32x4 __attribute__((ext_vector_type(4)));
typedef float f32x2 __attribute__((ext_vector_type(2)));

// r14 lesson: 2-node interleave doubled register demand -> spill. Kept: one
// 8-float accumulator per lane.
// r15/r16: phase-1 latency fix. Old shape = 16 sequential node segments/wave,
// each a full-wave dependent chain (rps/rpe -> col -> row -> shuffle-combine).
// New shape = 4 rounds x 4 nodes; each 16-lane quarter owns a full node -> 4
// independent chase streams, no cross-quarter shuffles, ranges/dis prefetched
// once per wave. fp8 pre-scaled gather rows kept (r14: FETCH floor 102MB
// confirmed). r16: acc helper reverted to r14-verified scalar-add form.

// ---- fp8 helpers (OCP e4m3 on gfx950) ----

__device__ __forceinline__ uint2 pack_fp8x8(const float* v) {
    int lo = 0, hi = 0;
    lo = __builtin_amdgcn_cvt_pk_fp8_f32(v[0], v[1], lo, false);
    lo = __builtin_amdgcn_cvt_pk_fp8_f32(v[2], v[3], lo, true);
    hi = __builtin_amdgcn_cvt_pk_fp8_f32(v[4], v[5], hi, false);
    hi = __builtin_amdgcn_cvt_pk_fp8_f32(v[6], v[7], hi, true);
    return (uint2){(unsigned)lo, (unsigned)hi};
}

__device__ __forceinline__ void acc_fp8x8(uint2 u, float* a) {
    f32x2 p0 = __builtin_amdgcn_cvt_pk_f32_fp8((int)u.x, false);
    f32x2 p1 = __builtin_amdgcn_cvt_pk_f32_fp8((int)u.x, true);
    f32x2 p2 = __builtin_amdgcn_cvt_pk_f32_fp8((int)u.y, false);
    f32x2 p3 = __builtin_amdgcn_cvt_pk_f32_fp8((int)u.y, true);
    a[0] += p0[0]; a[1] += p0[1]; a[2] += p1[0]; a[3] += p1[1];
    a[4] += p2[0]; a[5] += p2[1]; a[6] += p3[0]; a[7] += p3[1];
}

// ---------------- init ----------------

__global__ void k_init(int* __restrict__ bfill, int* __restrict__ gstart, int* __restrict__ gend) {
    int i = blockIdx.x * 256 + threadIdx.x;
    if (i <= NBKT) bfill[i] = 0;
    if (i < NG) { gstart[i] = 0x7fffffff; gend[i] = 0; }
}

// ---------------- bucketed CSR build ----------------

__global__ __launch_bounds__(256) void k_bscatter(const int* __restrict__ src, const int* __restrict__ dst,
                                                  int* __restrict__ bfill, unsigned int* __restrict__ ebuf) {
    __shared__ int lc[NBKT];
    __shared__ int lbase[NBKT];
    int t = threadIdx.x;
    for (int i = t; i < NBKT; i += 256) lc[i] = 0;
    __syncthreads();
    int base = blockIdx.x * EPB;
    int rank[16];
    int bk[16];
    unsigned pk[16];
#pragma unroll
    for (int i = 0; i < 16; i++) {
        int e = base + i * 256 + t;
        if (e < NE) {
            int d = dst[e];
            int s = src[e];
            int b = d >> 8;
            bk[i] = b;
            pk[i] = (unsigned)s | ((unsigned)(d & 255) << 17);
            rank[i] = atomicAdd(&lc[b], 1);
        } else bk[i] = -1;
    }
    __syncthreads();
    for (int i = t; i < NBKT; i += 256)
        lbase[i] = i * CAP + (lc[i] ? atomicAdd(&bfill[i], lc[i]) : 0);
    __syncthreads();
#pragma unroll
    for (int i = 0; i < 16; i++) {
        if (bk[i] >= 0)
            ebuf[lbase[bk[i]] + rank[i]] = pk[i];
    }
}

// One block per bucket (391 blocks): count -> dis, scan -> rps/rpe, scatter -> col.
__global__ __launch_bounds__(256) void k_bcsr(const unsigned int* __restrict__ ebuf,
                                              const int* __restrict__ bfill,
                                              int* __restrict__ rps, int* __restrict__ rpe,
                                              int* __restrict__ col, float* __restrict__ dis) {
    __shared__ int lcnt[256];
    __shared__ int lfill[256];
    __shared__ int tmp[256];
    int t = threadIdx.x;
    int b = blockIdx.x;
    int cb = b * CAP;
    int ecnt = bfill[b];
    int n0 = b << 8;
    int nb = min(256, NN - n0);

    lcnt[t] = 0;
    lfill[t] = 0;
    __syncthreads();

    for (int i = t; i < ecnt; i += 256) {
        unsigned p = ebuf[cb + i];
        atomicAdd(&lcnt[p >> 17], 1);
    }
    __syncthreads();

    if (t < nb) dis[n0 + t] = rsqrtf((float)(lcnt[t] + 1));

    int v = lcnt[t];
    tmp[t] = v;
    __syncthreads();
    for (int off = 1; off < 256; off <<= 1) {
        int x = (t >= off) ? tmp[t - off] : 0;
        __syncthreads();
        tmp[t] += x;
        __syncthreads();
    }
    lcnt[t] = tmp[t] - v;   // exclusive scan
    __syncthreads();

    if (t < nb) {
        rps[n0 + t] = cb + lcnt[t];
        rpe[n0 + t] = cb + ((t < 255) ? lcnt[t + 1] : ecnt);
    }

    for (int i = t; i < ecnt; i += 256) {
        unsigned p = ebuf[cb + i];
        int dl = p >> 17;
        int s = (int)(p & 0x1FFFFu);
        col[cb + lcnt[dl] + atomicAdd(&lfill[dl], 1)] = s;
    }
}

// ---------------- embed: hh = fp16(relu(x @ W_embed + b)); hp = fp8(hh * dis) ----------------

__global__ __launch_bounds__(256) void k_embed(const float* __restrict__ x, const float* __restrict__ W,
                                               const float* __restrict__ b, _Float16* __restrict__ hh,
                                               const float* __restrict__ dis, uint2* __restrict__ hp) {
    __shared__ float Ws[DIM0 * H];
    __shared__ float bs[H];
    __shared__ float xs[16 * DIM0];
    int tid = threadIdx.x;
    for (int i = tid; i < DIM0 * H; i += 256) Ws[i] = W[i];
    if (tid < H) bs[tid] = b[tid];
    if (tid < 16 * DIM0) xs[tid] = x[(size_t)blockIdx.x * (16 * DIM0) + tid];
    __syncthreads();
    int nl = tid >> 4;
    int node = blockIdx.x * 16 + nl;
    int l4 = tid & 15;
    float dn = dis[node];
    f16x8 o;
    float hv[8];
#pragma unroll
    for (int j = 0; j < 8; j++) {
        int c = l4 * 8 + j;
        float acc = bs[c];
#pragma unroll
        for (int k = 0; k < DIM0; k++) acc += xs[nl * DIM0 + k] * Ws[k * H + c];
        float r = fmaxf(acc, 0.f);
        o[j] = (_Float16)r;
        hv[j] = r * dn;
    }
    *(f16x8*)&hh[(size_t)node * H + l4 * 8] = o;
    hp[(size_t)node * 16 + l4] = pack_fp8x8(hv);
}

// ---------------- W pack: W[l][k][n] fp32 -> B-fragment-layout fp16 ----------------

__global__ __launch_bounds__(256) void k_wpack(const float* __restrict__ W, _Float16* __restrict__ Wp) {
    int t = blockIdx.x * 256 + threadIdx.x;   // 8192 threads
    int lane = t & 63;
    int idx = t >> 6;          // 0..127
    int nt = idx & 7;
    int ks = (idx >> 3) & 3;
    int l = idx >> 5;
    int q = lane >> 4, l15 = lane & 15;
    const float* Wl = W + (size_t)l * H * H;
    _Float16* o = Wp + (size_t)idx * 512 + lane * 8;
#pragma unroll
    for (int j = 0; j < 8; j++)
        o[j] = (_Float16)(Wl[(ks * 32 + q * 8 + j) * H + nt * 16 + l15]);
}

// ---------------- fused layer: hout = relu(LN(agg(hin) @ W + b)) + hin ----------------
// Phase 1 (r15 shape): 4 rounds; each 16-lane quarter owns one node fully.
// 4 independent load-chase streams per wave, no cross-quarter shuffles.
// Ranges/dis prefetched once per wave (3 coalesced loads + shfl broadcast).

__global__ __launch_bounds__(128, 8) void k_layer(const _Float16* __restrict__ hin,
                                                  _Float16* __restrict__ hout,
                                                  const uint2* __restrict__ hpin,
                                                  uint2* __restrict__ hpout,
                                                  const float* __restrict__ dis, const int* __restrict__ rps,
                                                  const int* __restrict__ rpe, const int* __restrict__ col,
                                                  const _Float16* __restrict__ Wp,
                                                  const float* __restrict__ bias,
                                                  const float* __restrict__ gamma,
                                                  const float* __restrict__ beta,
                                                  int store_hp) {
    __shared__ _Float16 Ls[2][16][136];   // 8704 B
    int tid = threadIdx.x;
    int wave = tid >> 6;
    int lane = tid & 63;
    int q = lane >> 4, l4 = lane & 15;
    int nbase = blockIdx.x * 32 + wave * 16;   // 32 | NN, no tail

    // wave-wide prefetch of the 16 nodes' CSR ranges + dis
    int l16 = lane & 15;
    int ev0 = rps[nbase + l16];
    int ev1 = rpe[nbase + l16];
    float dv = dis[nbase + l16];

    // ---- phase 1: gather 16 nodes into Ls, 4 nodes per round ----
#pragma unroll 1
    for (int r = 0; r < 4; r++) {
        int nl = r * 4 + q;                 // node slot owned by this quarter
        int e0 = __shfl(ev0, nl, 64);
        int e1 = __shfl(ev1, nl, 64);
        float dn = __shfl(dv, nl, 64);
        int node = nbase + nl;

        float a[8];
#pragma unroll
        for (int j = 0; j < 8; j++) a[j] = 0.f;

        uint2 sv = hpin[(size_t)node * 16 + l4];   // self row (pre-scaled), issued early

        int e = e0;
#pragma unroll 1
        for (; e + 3 < e1; e += 4) {
            int s0 = col[e];
            int s1 = col[e + 1];
            int s2 = col[e + 2];
            int s3 = col[e + 3];
            uint2 v0 = hpin[(size_t)s0 * 16 + l4];
            uint2 v1 = hpin[(size_t)s1 * 16 + l4];
            uint2 v2 = hpin[(size_t)s2 * 16 + l4];
            uint2 v3 = hpin[(size_t)s3 * 16 + l4];
            acc_fp8x8(v0, a);
            acc_fp8x8(v1, a);
            acc_fp8x8(v2, a);
            acc_fp8x8(v3, a);
        }
#pragma unroll 1
        for (; e < e1; e++) {
            int s = col[e];
            uint2 v = hpin[(size_t)s * 16 + l4];
            acc_fp8x8(v, a);
        }
        acc_fp8x8(sv, a);   // self-loop

        f16x8 o;
#pragma unroll
        for (int j = 0; j < 8; j++) o[j] = (_Float16)(a[j] * dn);
        *(f16x8*)&Ls[wave][nl][l4 * 8] = o;
    }

    // ---- phase 2: read A-fragments into registers, then GEMM + LN (Ls reused) ----
    f16x8 af[4];
#pragma unroll
    for (int ks = 0; ks < 4; ks++)
        af[ks] = *(const f16x8*)&Ls[wave][l4][ks * 32 + q * 8];

    float bb[8], gm[8], bt[8];
#pragma unroll
    for (int nt = 0; nt < 8; nt++) {
        bb[nt] = bias[nt * 16 + l4];
        gm[nt] = gamma[nt * 16 + l4];
        bt[nt] = beta[nt * 16 + l4];
    }

    const f16x8* wp8 = (const f16x8*)Wp;
    f32x4 acc[8];
#pragma unroll
    for (int nt = 0; nt < 8; nt++) {
        acc[nt] = (f32x4){0.f, 0.f, 0.f, 0.f};
#pragma unroll
        for (int ks = 0; ks < 4; ks++) {
            f16x8 bf = wp8[(ks * 8 + nt) * 64 + lane];
            acc[nt] = __builtin_amdgcn_mfma_f32_16x16x32_f16(af[ks], bf, acc[nt], 0, 0, 0);
        }
#pragma unroll
        for (int r = 0; r < 4; r++) acc[nt][r] += bb[nt];
    }

    float mu[4], rs[4];
#pragma unroll
    for (int r = 0; r < 4; r++) {
        float s = 0.f;
#pragma unroll
        for (int nt = 0; nt < 8; nt++) s += acc[nt][r];
#pragma unroll
        for (int off = 8; off > 0; off >>= 1) s += __shfl_xor(s, off, 64);
        mu[r] = s * (1.f / 128.f);
    }
#pragma unroll
    for (int r = 0; r < 4; r++) {
        float v = 0.f;
#pragma unroll
        for (int nt = 0; nt < 8; nt++) {
            float d = acc[nt][r] - mu[r];
            v += d * d;
        }
#pragma unroll
        for (int off = 8; off > 0; off >>= 1) v += __shfl_xor(v, off, 64);
        rs[r] = rsqrtf(v * (1.f / 128.f) + EPS);
    }

    // overwrite Ls with LN output (af already in registers)
#pragma unroll
    for (int nt = 0; nt < 8; nt++)
#pragma unroll
        for (int r = 0; r < 4; r++) {
            float o = fmaxf((acc[nt][r] - mu[r]) * rs[r] * gm[nt] + bt[nt], 0.f);
            Ls[wave][q * 4 + r][nt * 16 + l4] = (_Float16)o;
        }

    // epilogue: residual add (hin) + coalesced store to hout + fp8 gather copy
    const f16x8* hi8 = (const f16x8*)hin;
    f16x8* ho8 = (f16x8*)hout;
#pragma unroll
    for (int it = 0; it < 4; it++) {
        int c = it * 64 + lane;
        int rr = c >> 4, ck = c & 15;   // rr = it*4 + q
        int row = nbase + rr;
        f16x8 ln = *(const f16x8*)&Ls[wave][rr][ck * 8];
        f16x8 res = hi8[(size_t)row * 16 + ck];
        float dn2 = __shfl(dv, rr, 64);
        f16x8 o;
        float hv[8];
#pragma unroll
        for (int j = 0; j < 8; j++) {
            float s = (float)ln[j] + (float)res[j];
            o[j] = (_Float16)s;
            hv[j] = s * dn2;
        }
        ho8[(size_t)row * 16 + ck] = o;
        if (store_hp)
            hpout[(size_t)row * 16 + ck] = pack_fp8x8(hv);
    }
}

// ---------------- pooling ----------------

__global__ void k_range(const int* __restrict__ batch, int* __restrict__ gstart, int* __restrict__ gend) {
    int n = blockIdx.x * 256 + threadIdx.x;
    if (n < NN) {
        int g = batch[n];
        atomicMin(&gstart[g], n);
        atomicMax(&gend[g], n + 1);
    }
}

// One wave per graph; lane = (node slot p4, col group l4); f16x8 loads, 4 nodes/iter.
__global__ __launch_bounds__(256) void k_pool(const _Float16* __restrict__ hh, const int* __restrict__ gstart,
                                              const int* __restrict__ gend, const float* __restrict__ Wout,
                                              const float* __restrict__ bout, float* __restrict__ out) {
    int tid = threadIdx.x;
    int lane = tid & 63;
    int p4 = lane >> 4;     // node slot 0..3
    int l4 = lane & 15;     // cols l4*8 .. +7
    int g = blockIdx.x * 4 + (tid >> 6);
    if (g >= NG) return;

    int s = gstart[g], e = gend[g];
    const f16x8* h8 = (const f16x8*)hh;
    float acc[8];
#pragma unroll
    for (int j = 0; j < 8; j++) acc[j] = 0.f;
    for (int n = s + p4; n < e; n += 4) {
        f16x8 v = h8[(size_t)n * 16 + l4];
#pragma unroll
        for (int j = 0; j < 8; j++) acc[j] += (float)v[j];
    }
    // combine node slots
#pragma unroll
    for (int j = 0; j < 8; j++) {
        acc[j] += __shfl_xor(acc[j], 16, 64);
        acc[j] += __shfl_xor(acc[j], 32, 64);
    }
    float p = 0.f;
#pragma unroll
    for (int j = 0; j < 8; j++) p += acc[j] * Wout[l4 * 8 + j];
    // reduce across the 16 col groups
#pragma unroll
    for (int off = 8; off > 0; off >>= 1) p += __shfl_xor(p, off, 64);
    if (lane == 0) {
        float inv = 1.f / (float)max(e - s, 1);
        out[g] = p * inv + bout[0];
    }
}

// ---------------- launcher ----------------

extern "C" void kernel_launch(void* const* d_in, const int* in_sizes, int n_in,
                              void* d_out, int out_size, void* d_ws, size_t ws_size,
                              hipStream_t stream) {
    const float* x       = (const float*)d_in[0];
    const int*   edge    = (const int*)d_in[1];
    const int*   batch   = (const int*)d_in[2];
    const float* W_embed = (const float*)d_in[3];
    const float* b_embed = (const float*)d_in[4];
    const float* W_gnn   = (const float*)d_in[5];
    const float* b_gnn   = (const float*)d_in[6];
    const float* gamma   = (const float*)d_in[7];
    const float* beta    = (const float*)d_in[8];
    const float* W_out   = (const float*)d_in[9];
    const float* b_out   = (const float*)d_in[10];
    float* out = (float*)d_out;

    char* ws = (char*)d_ws;
    size_t off = 0;
    auto alloc = [&](size_t bytes) -> char* {
        char* p = ws + off;
        off += (bytes + 255) & ~(size_t)255;
        return p;
    };
    _Float16*     hh0  = (_Float16*)alloc((size_t)NN * H * 2);
    _Float16*     hh1  = (_Float16*)alloc((size_t)NN * H * 2);
    uint2*        hp0  = (uint2*)alloc((size_t)NN * H);       // fp8 gather copies
    uint2*        hp1  = (uint2*)alloc((size_t)NN * H);
    _Float16*     Wp   = (_Float16*)alloc((size_t)NL * 4 * 8 * 512 * 2);
    float*        dis  = (float*)alloc((size_t)NN * 4);
    int*          rps  = (int*)alloc((size_t)NN * 4);
    int*          rpe  = (int*)alloc((size_t)NN * 4);
    int*          col  = (int*)alloc((size_t)NBKT * CAP * 4);
    unsigned int* ebuf = (unsigned int*)alloc((size_t)NBKT * CAP * 4);
    int*          bfill = (int*)alloc((NBKT + 1) * 4);
    int*   gstart = (int*)alloc((size_t)NG * 4);
    int*   gend   = (int*)alloc((size_t)NG * 4);

    const int* srcp = edge;
    const int* dstp = edge + NE;

    k_init<<<(NG + 255) / 256, 256, 0, stream>>>(bfill, gstart, gend);
    k_bscatter<<<NBB, 256, 0, stream>>>(srcp, dstp, bfill, ebuf);
    k_bcsr<<<NBKT, 256, 0, stream>>>(ebuf, bfill, rps, rpe, col, dis);

    k_wpack<<<32, 256, 0, stream>>>(W_gnn, Wp);
    k_embed<<<NN / 16, 256, 0, stream>>>(x, W_embed, b_embed, hh0, dis, hp0);

    // ping-pong: L0 hh0->hh1, L1 hh1->hh0, L2 hh0->hh1, L3 hh1->hh0
    _Float16* hb[2] = {hh0, hh1};
    uint2*    hp[2] = {hp0, hp1};
    for (int l = 0; l < NL; l++) {
        k_layer<<<(NN + 31) / 32, 128, 0, stream>>>(hb[l & 1], hb[(l & 1) ^ 1],
                                                    hp[l & 1], hp[(l & 1) ^ 1],
                                                    dis, rps, rpe, col,
                                                    Wp + (size_t)l * 4 * 8 * 512,
                                                    b_gnn + l * H, gamma + l * H, beta + l * H,
                                                    (l != NL - 1) ? 1 : 0);
    }

    k_range<<<(NN + 255) / 256, 256, 0, stream>>>(batch, gstart, gend);
    k_pool<<<NG / 4, 256, 0, stream>>>(hh0, gstart, gend, W_out, b_out, out);
}